// Round 9
// baseline (242.397 us; speedup 1.0000x reference)
//
#include <hip/hip_runtime.h>
#include <hip/hip_bf16.h>

#define Bz 4
#define Sz 2048
#define Dz 1024
#define Hz 16
#define DHz 64
#define Mz (Bz*Sz)      // 8192
#define N3z (3*Dz)      // 3072
#define Kz Dz           // 1024

typedef short s16x8 __attribute__((ext_vector_type(8)));
typedef float f32x4 __attribute__((ext_vector_type(4)));
typedef unsigned short u16;

__device__ __forceinline__ u16 f2b(float f) {
  union { float f; unsigned u; } v; v.f = f;
  unsigned r = v.u + 0x7FFFu + ((v.u >> 16) & 1u);
  return (u16)(r >> 16);
}

__device__ __forceinline__ unsigned cvt_pk_bf16(float lo, float hi) {
  unsigned r;
  asm("v_cvt_pk_bf16_f32 %0, %1, %2" : "=v"(r) : "v"(lo), "v"(hi));
  return r;
}

// ---------------- x (f32) -> bf16, linear ----------------
__global__ __launch_bounds__(256) void cvt_x(const float* __restrict__ x,
                                             u16* __restrict__ xb) {
  int i = (blockIdx.x * 256 + threadIdx.x) * 4;
  float4 v = *reinterpret_cast<const float4*>(x + i);
  ushort4 o;
  o.x = f2b(v.x); o.y = f2b(v.y); o.z = f2b(v.z); o.w = f2b(v.w);
  *reinterpret_cast<ushort4*>(xb + i) = o;
}

// ---------------- W [K][3D] f32 -> Wt [3D][K] bf16 ----------------
__global__ __launch_bounds__(256) void transpose_w(const float* __restrict__ W,
                                                   u16* __restrict__ Wt) {
  __shared__ u16 t[32][33];
  int nb = blockIdx.x;
  int kb = blockIdx.y;
  int tx = threadIdx.x, ty = threadIdx.y;
#pragma unroll
  for (int j = 0; j < 4; ++j) {
    int k = kb * 32 + ty + j * 8;
    t[ty + j * 8][tx] = f2b(W[(size_t)k * N3z + nb * 32 + tx]);
  }
  __syncthreads();
#pragma unroll
  for (int j = 0; j < 4; ++j) {
    int n = nb * 32 + ty + j * 8;
    Wt[(size_t)n * Kz + kb * 32 + tx] = t[tx][ty + j * 8];
  }
}

// ---------------- QKV GEMM: [8192,1024] x [1024,3072] + bias ----------------
// BK=64, T2 both-sides swizzle (pre-swizzled global source, XOR read).
// T1 XCD swizzle: per-XCD band of 8 M-tiles (A-panel 2MB L2-resident).
// Epilogue: Q scaled by log2e/8; V written TRANSPOSED -> Vt[b][h][dh][s].
#define BM 128
#define BN 128
#define BKs 64
#define QSCALE (0.125f * 1.44269504088896f)   // 1/sqrt(64) * log2(e)

__global__ __launch_bounds__(256) void qkv_gemm(
    const u16* __restrict__ A, const u16* __restrict__ Bt,
    const float* __restrict__ bias,
    u16* __restrict__ Qo, u16* __restrict__ Ko, u16* __restrict__ Vt) {
  __shared__ alignas(16) u16 As[BM * BKs];   // 16 KB
  __shared__ alignas(16) u16 Bs[BN * BKs];   // 16 KB
  const int tid = threadIdx.x;
  const int wid = tid >> 6, lane = tid & 63;
  const int wr = wid >> 1, wc = wid & 1;
  const int g = lane >> 4, lq = lane & 15;

  // XCD-aware block swizzle (bijective: 1536 % 8 == 0)
  const int id = blockIdx.x + gridDim.x * blockIdx.y;   // 0..1535
  const int xc = id & 7, rr = id >> 3;                  // rr 0..191
  const int bx = xc * 8 + (rr & 7);                     // 0..63  (M-tile)
  const int by = rr >> 3;                               // 0..23  (N-tile)
  const int brow = bx * BM;
  const int bcol = by * BN;

  const int soff = (((lane & 7) ^ (lane >> 3))) * 8;    // pre-swizzled source

  f32x4 acc[4][4] = {};

  for (int kt = 0; kt < Kz; kt += BKs) {
#pragma unroll
    for (int c = 0; c < 4; ++c) {
      int row = (wid * 4 + c) * 8 + (lane >> 3);
      const u16* ga = A + (size_t)(brow + row) * Kz + kt + soff;
      __builtin_amdgcn_global_load_lds(
          (const __attribute__((address_space(1))) void*)ga,
          (__attribute__((address_space(3))) void*)&As[(wid * 4 + c) * 512],
          16, 0, 0);
      const u16* gb = Bt + (size_t)(bcol + row) * Kz + kt + soff;
      __builtin_amdgcn_global_load_lds(
          (const __attribute__((address_space(1))) void*)gb,
          (__attribute__((address_space(3))) void*)&Bs[(wid * 4 + c) * 512],
          16, 0, 0);
    }
    __syncthreads();

#pragma unroll
    for (int ks = 0; ks < 2; ++ks) {
      s16x8 af[4], bfr[4];
#pragma unroll
      for (int i = 0; i < 4; ++i) {
        int rowa = wr * 64 + i * 16 + lq;
        int rowb = wc * 64 + i * 16 + lq;
        int sl = ((ks * 4 + g) ^ (lq & 7)) << 4;
        af[i]  = *reinterpret_cast<const s16x8*>((const char*)As + rowa * 128 + sl);
        bfr[i] = *reinterpret_cast<const s16x8*>((const char*)Bs + rowb * 128 + sl);
      }
#pragma unroll
      for (int mi = 0; mi < 4; ++mi)
#pragma unroll
        for (int ni = 0; ni < 4; ++ni)
          acc[mi][ni] = __builtin_amdgcn_mfma_f32_16x16x32_bf16(af[mi], bfr[ni], acc[mi][ni], 0, 0, 0);
    }
    __syncthreads();
  }

#pragma unroll
  for (int ni = 0; ni < 4; ++ni) {
    int gcol = bcol + wc * 64 + ni * 16 + lq;
    int h = gcol / 192;
    int rem = gcol - h * 192;
    int tt = rem >> 6;
    int dh = rem & 63;
    float bv = bias[gcol];
    u16* dst = (tt == 0) ? Qo : (tt == 1) ? Ko : Vt;
    float scale = (tt == 0) ? QSCALE : 1.0f;
    bool isv = (tt == 2);
#pragma unroll
    for (int mi = 0; mi < 4; ++mi) {
#pragma unroll
      for (int r = 0; r < 4; ++r) {
        int grow = brow + wr * 64 + mi * 16 + g * 4 + r;
        int bb = grow >> 11;
        int ss = grow & 2047;
        float v = (acc[mi][ni][r] + bv) * scale;
        size_t off = isv ? ((((size_t)bb * Hz + h) * DHz + dh) * Sz + ss)
                         : ((((size_t)bb * Hz + h) * Sz + ss) * DHz + dh);
        dst[off] = f2b(v);
      }
    }
  }
}

// ---------------- causal flash attention ----------------
// grid (8,64) XCD-swizzled (per-XCD bh-chunk of 8 -> KV/XCD = 4MB = L2).
// Block owns q-tiles qp AND 15-qp in ONE merged t-loop: each KV tile staged
// ONCE serves both (ntA <= ntB always). Staging = 2x global_load_lds per
// thread per tile (K rows + Vt rows; pre-swizzled source, zero staging VALU).
// Double-buffered; one barrier per tile. Swapped QK^T + in-register softmax
// (T12), exp2 domain, defer-max (T13), paired-shfl P redistribution.
__device__ __forceinline__ void attn_tile(
    const char* KsC, const char* VsC, int kv0, int q0w, int qrow,
    int g, int lq, int p, int cb, int sEven, int sOdd,
    const s16x8& qf0, const s16x8& qf1,
    f32x4 (&o)[4], float& m1, float& l1) {
  if (kv0 > q0w + 15) return;   // wave-uniform

  // ---- swapped QK^T: z[f][r] = S[q=lq][key=kv0+f*16+g*4+r] ----
  f32x4 z[4];
#pragma unroll
  for (int f = 0; f < 4; ++f) {
    int row = f * 16 + lq;
    s16x8 kb0 = *reinterpret_cast<const s16x8*>(KsC + row * 128 + ((g ^ (row & 7)) << 4));
    s16x8 kb1 = *reinterpret_cast<const s16x8*>(KsC + row * 128 + (((g + 4) ^ (row & 7)) << 4));
    f32x4 zz = {0.f, 0.f, 0.f, 0.f};
    zz = __builtin_amdgcn_mfma_f32_16x16x32_bf16(kb0, qf0, zz, 0, 0, 0);
    zz = __builtin_amdgcn_mfma_f32_16x16x32_bf16(kb1, qf1, zz, 0, 0, 0);
    z[f] = zz;
  }

  if (kv0 + 63 > q0w) {  // diagonal tile: causal mask (key > q)
#pragma unroll
    for (int f = 0; f < 4; ++f)
#pragma unroll
      for (int r = 0; r < 4; ++r) {
        int key = kv0 + f * 16 + g * 4 + r;
        if (key > qrow) z[f][r] = -1e30f;
      }
  }

  // ---- row max ----
  float pm = z[0][0];
#pragma unroll
  for (int f = 0; f < 4; ++f)
#pragma unroll
    for (int r = 0; r < 4; ++r) pm = fmaxf(pm, z[f][r]);
  pm = fmaxf(pm, __shfl_xor(pm, 16));
  pm = fmaxf(pm, __shfl_xor(pm, 32));

  // ---- T13 defer-max ----
  if (!__all(pm <= m1 + 8.0f)) {
    float mn = fmaxf(m1, pm);
    float a = exp2f(m1 - mn);
    m1 = mn;
    l1 *= a;
    float a0 = __shfl(a, 4 * g + 0);
    float a1 = __shfl(a, 4 * g + 1);
    float a2 = __shfl(a, 4 * g + 2);
    float a3 = __shfl(a, 4 * g + 3);
#pragma unroll
    for (int ni = 0; ni < 4; ++ni) {
      o[ni][0] *= a0; o[ni][1] *= a1; o[ni][2] *= a2; o[ni][3] *= a3;
    }
  }

  // ---- p = exp2(z - m), sum, pack ----
  float s = 0.f;
  unsigned w[4][2];
#pragma unroll
  for (int f = 0; f < 4; ++f) {
    float p0 = exp2f(z[f][0] - m1);
    float p1 = exp2f(z[f][1] - m1);
    float p2 = exp2f(z[f][2] - m1);
    float p3 = exp2f(z[f][3] - m1);
    s += (p0 + p1) + (p2 + p3);
    w[f][0] = cvt_pk_bf16(p0, p1);
    w[f][1] = cvt_pk_bf16(p2, p3);
  }
  s += __shfl_xor(s, 16);
  s += __shfl_xor(s, 32);
  l1 += s;

  // ---- redistribute P into PV A-fragments: 8 paired shfls ----
  int e0 = __shfl((int)(p ? w[1][0] : w[0][0]), sEven);
  int o0 = __shfl((int)(p ? w[0][0] : w[1][0]), sOdd);
  int e1 = __shfl((int)(p ? w[1][1] : w[0][1]), sEven);
  int o1 = __shfl((int)(p ? w[0][1] : w[1][1]), sOdd);
  int e2 = __shfl((int)(p ? w[3][0] : w[2][0]), sEven);
  int o2 = __shfl((int)(p ? w[2][0] : w[3][0]), sOdd);
  int e3 = __shfl((int)(p ? w[3][1] : w[2][1]), sEven);
  int o3 = __shfl((int)(p ? w[2][1] : w[3][1]), sOdd);
  union { int i[4]; s16x8 v; } A0, A1;
  A0.i[0] = cb ? o0 : e0;
  A0.i[2] = cb ? e0 : o0;
  A0.i[1] = cb ? o1 : e1;
  A0.i[3] = cb ? e1 : o1;
  A1.i[0] = cb ? o2 : e2;
  A1.i[2] = cb ? e2 : o2;
  A1.i[1] = cb ? o3 : e3;
  A1.i[3] = cb ? e3 : o3;

  // ---- PV ----
#pragma unroll
  for (int ni = 0; ni < 4; ++ni) {
    int row = ni * 16 + lq;
    s16x8 vb0 = *reinterpret_cast<const s16x8*>(VsC + row * 128 + ((g ^ (row & 7)) << 4));
    s16x8 vb1 = *reinterpret_cast<const s16x8*>(VsC + row * 128 + (((g + 4) ^ (row & 7)) << 4));
    o[ni] = __builtin_amdgcn_mfma_f32_16x16x32_bf16(A0.v, vb0, o[ni], 0, 0, 0);
    o[ni] = __builtin_amdgcn_mfma_f32_16x16x32_bf16(A1.v, vb1, o[ni], 0, 0, 0);
  }
}

__global__ __launch_bounds__(512, 4) void attn_kernel(
    const u16* __restrict__ Qg, const u16* __restrict__ Kg,
    const u16* __restrict__ Vtg, float* __restrict__ out) {
  __shared__ alignas(16) u16 Ks[2][64 * 64];      // swizzled K [key][dh]
  __shared__ alignas(16) u16 Vs[2][64 * 64];      // swizzled V^T [dh][key]

  const int tid = threadIdx.x;
  const int wid = tid >> 6, lane = tid & 63;
  const int g = lane >> 4, lq = lane & 15;

  // XCD-aware swizzle (bijective: 512 % 8 == 0): per-XCD bh-chunk of 8
  const int id = blockIdx.x + 8 * blockIdx.y;
  const int xc = id & 7, rr = id >> 3;            // rr 0..63
  const int bh = xc * 8 + (rr & 7);
  const int qp = rr >> 3;                         // 0..7

  const size_t base = (size_t)bh * Sz * DHz;      // K (and Q) base; Vt same size
  const int b = bh >> 4, h = bh & 15;

  const int krow = tid >> 3;                      // row within tile (key or dh)
  const int sswz = ((tid & 7) ^ (krow & 7)) * 8;  // pre-swizzled source offset

  // P-redistribution geometry (round-5-verified)
  const int p = g & 1;
  const int cb = g >> 1;
  const int sA = 32 * (g & 1) + lq;
  const int sB = sA + 16;
  const int sEven = cb ? sB : sA;
  const int sOdd  = cb ? sA : sB;

  const int qtA = qp, qtB = 15 - qp;
  const int q0wA = qtA * 128 + wid * 16;
  const int q0wB = qtB * 128 + wid * 16;
  const int qrowA = q0wA + lq, qrowB = q0wB + lq;
  const int ntA = 2 * qtA + 2, ntB = 2 * qtB + 2;   // ntA <= ntB

  s16x8 qfA0 = *reinterpret_cast<const s16x8*>(Qg + base + (size_t)qrowA * DHz + g * 8);
  s16x8 qfA1 = *reinterpret_cast<const s16x8*>(Qg + base + (size_t)qrowA * DHz + g * 8 + 32);
  s16x8 qfB0 = *reinterpret_cast<const s16x8*>(Qg + base + (size_t)qrowB * DHz + g * 8);
  s16x8 qfB1 = *reinterpret_cast<const s16x8*>(Qg + base + (size_t)qrowB * DHz + g * 8 + 32);

  f32x4 oA[4] = {}, oB[4] = {};
  float mA = -1e30f, lA = 0.f, mB = -1e30f, lB = 0.f;

  // ---- prologue: DMA tile 0 into buf 0 ----
  {
    const u16* gk = Kg + base + (size_t)krow * DHz + sswz;
    __builtin_amdgcn_global_load_lds(
        (const __attribute__((address_space(1))) void*)gk,
        (__attribute__((address_space(3))) void*)&Ks[0][wid * 512], 16, 0, 0);
    const u16* gv = Vtg + base + (size_t)krow * Sz + sswz;
    __builtin_amdgcn_global_load_lds(
        (const __attribute__((address_space(1))) void*)gv,
        (__attribute__((address_space(3))) void*)&Vs[0][wid * 512], 16, 0, 0);
  }
  __syncthreads();

  int cur = 0;
  for (int t = 0; t < ntB; ++t) {
    const int kv0 = t * 64;

    // ---- DMA next tile into other buffer (drained by loop-end barrier) ----
    if (t + 1 < ntB) {
      const int nv0 = kv0 + 64;
      const u16* gk = Kg + base + (size_t)(nv0 + krow) * DHz + sswz;
      __builtin_amdgcn_global_load_lds(
          (const __attribute__((address_space(1))) void*)gk,
          (__attribute__((address_space(3))) void*)&Ks[cur ^ 1][wid * 512], 16, 0, 0);
      const u16* gv = Vtg + base + (size_t)krow * Sz + nv0 + sswz;
      __builtin_amdgcn_global_load_lds(
          (const __attribute__((address_space(1))) void*)gv,
          (__attribute__((address_space(3))) void*)&Vs[cur ^ 1][wid * 512], 16, 0, 0);
    }

    const char* KsC = (const char*)Ks[cur];
    const char* VsC = (const char*)Vs[cur];

    attn_tile(KsC, VsC, kv0, q0wB, qrowB, g, lq, p, cb, sEven, sOdd,
              qfB0, qfB1, oB, mB, lB);
    if (t < ntA)
      attn_tile(KsC, VsC, kv0, q0wA, qrowA, g, lq, p, cb, sEven, sOdd,
                qfA0, qfA1, oA, mA, lA);

    __syncthreads();
    cur ^= 1;
  }

  // ---- write out [B][S][H][DH] f32 for both q-tiles ----
#pragma unroll
  for (int half = 0; half < 2; ++half) {
    const int q0w = half ? q0wB : q0wA;
    f32x4* o = half ? oB : oA;
    float l1 = half ? lB : lA;
    float lr0 = __shfl(l1, 4 * g + 0);
    float lr1 = __shfl(l1, 4 * g + 1);
    float lr2 = __shfl(l1, 4 * g + 2);
    float lr3 = __shfl(l1, 4 * g + 3);
    float inv[4] = {1.0f / lr0, 1.0f / lr1, 1.0f / lr2, 1.0f / lr3};
#pragma unroll
    for (int r = 0; r < 4; ++r) {
      int s = q0w + g * 4 + r;
      float* op = out + (((size_t)b * Sz + s) * Hz + h) * DHz;
#pragma unroll
      for (int ni = 0; ni < 4; ++ni)
        op[ni * 16 + lq] = o[ni][r] * inv[r];
    }
  }
}

extern "C" void kernel_launch(void* const* d_in, const int* in_sizes, int n_in,
                              void* d_out, int out_size, void* d_ws, size_t ws_size,
                              hipStream_t stream) {
  const float* x    = (const float*)d_in[0];
  const float* W    = (const float*)d_in[1];
  const float* bias = (const float*)d_in[2];
  float* out = (float*)d_out;

  char* ws = (char*)d_ws;
  u16* xb = (u16*)(ws);                      // 16 MB
  u16* wt = (u16*)(ws + 16777216);           // 6 MB
  u16* Qb = (u16*)(ws + 23068672);           // 16 MB
  u16* Kb = (u16*)(ws + 39845888);           // 16 MB
  u16* Vtb = (u16*)(ws + 56623104);          // 16 MB  (transposed: [b][h][dh][s])

  cvt_x<<<8192, 256, 0, stream>>>(x, xb);
  transpose_w<<<dim3(96, 32), dim3(32, 8), 0, stream>>>(W, wt);
  qkv_gemm<<<dim3(Mz / BM, N3z / BN), 256, 0, stream>>>(xb, wt, bias, Qb, Kb, Vtb);
  attn_kernel<<<dim3(8, Bz * Hz), 512, 0, stream>>>(Qb, Kb, Vtb, out);
}

// Round 10
// 234.796 us; speedup vs baseline: 1.0324x; 1.0324x over previous
//
#include <hip/hip_runtime.h>
#include <hip/hip_bf16.h>

#define Bz 4
#define Sz 2048
#define Dz 1024
#define Hz 16
#define DHz 64
#define Mz (Bz*Sz)      // 8192
#define N3z (3*Dz)      // 3072
#define Kz Dz           // 1024

typedef short s16x8 __attribute__((ext_vector_type(8)));
typedef float f32x4 __attribute__((ext_vector_type(4)));
typedef unsigned short u16;

__device__ __forceinline__ u16 f2b(float f) {
  union { float f; unsigned u; } v; v.f = f;
  unsigned r = v.u + 0x7FFFu + ((v.u >> 16) & 1u);
  return (u16)(r >> 16);
}

__device__ __forceinline__ unsigned cvt_pk_bf16(float lo, float hi) {
  unsigned r;
  asm("v_cvt_pk_bf16_f32 %0, %1, %2" : "=v"(r) : "v"(lo), "v"(hi));
  return r;
}

// ---------------- fused prep: x->bf16  +  W -> Wt bf16 ----------------
// blocks [0,8192): cvt_x; blocks [8192,11264): transpose_w (flattened 2D).
__global__ __launch_bounds__(256) void prep(const float* __restrict__ x,
                                            u16* __restrict__ xb,
                                            const float* __restrict__ W,
                                            u16* __restrict__ Wt) {
  __shared__ u16 t[32][33];
  const int bid = blockIdx.x;
  const int tid = threadIdx.x;
  if (bid < 8192) {
    int i = (bid * 256 + tid) * 4;
    float4 v = *reinterpret_cast<const float4*>(x + i);
    ushort4 o;
    o.x = f2b(v.x); o.y = f2b(v.y); o.z = f2b(v.z); o.w = f2b(v.w);
    *reinterpret_cast<ushort4*>(xb + i) = o;
  } else {
    int id2 = bid - 8192;           // 0..3071
    int nb = id2 % 96;              // N-tile (3072/32)
    int kb = id2 / 96;              // K-tile (1024/32)
    int tx = tid & 31, ty = tid >> 5;
#pragma unroll
    for (int j = 0; j < 4; ++j) {
      int k = kb * 32 + ty + j * 8;
      t[ty + j * 8][tx] = f2b(W[(size_t)k * N3z + nb * 32 + tx]);
    }
    __syncthreads();
#pragma unroll
    for (int j = 0; j < 4; ++j) {
      int n = nb * 32 + ty + j * 8;
      Wt[(size_t)n * Kz + kb * 32 + tx] = t[tx][ty + j * 8];
    }
  }
}

// ---------------- QKV GEMM (round-5 structure, fastest observed) ----------
// BK=32, linear LDS, natural block order. Epilogue: Q scaled by log2e/8;
// V written TRANSPOSED -> Vt[b][h][dh][s] (attn consumes it via DMA).
#define BM 128
#define BN 128
#define BKs 32
#define QSCALE (0.125f * 1.44269504088896f)   // 1/sqrt(64) * log2(e)

__global__ __launch_bounds__(256) void qkv_gemm(
    const u16* __restrict__ A, const u16* __restrict__ Bt,
    const float* __restrict__ bias,
    u16* __restrict__ Qo, u16* __restrict__ Ko, u16* __restrict__ Vt) {
  __shared__ alignas(16) u16 As[BM * BKs];   // 8 KB
  __shared__ alignas(16) u16 Bs[BN * BKs];   // 8 KB
  const int tid = threadIdx.x;
  const int wid = tid >> 6, lane = tid & 63;
  const int wr = wid >> 1, wc = wid & 1;
  const int g = lane >> 4, lq = lane & 15;
  const int brow = blockIdx.x * BM;
  const int bcol = blockIdx.y * BN;

  f32x4 acc[4][4] = {};

  for (int kt = 0; kt < Kz; kt += BKs) {
#pragma unroll
    for (int c = 0; c < 2; ++c) {
      int row = (wid * 2 + c) * 16 + (lane >> 2);
      int off = (lane & 3) * 8;
      const u16* ga = A + (size_t)(brow + row) * Kz + kt + off;
      __builtin_amdgcn_global_load_lds(
          (const __attribute__((address_space(1))) void*)ga,
          (__attribute__((address_space(3))) void*)&As[(wid * 2 + c) * 512],
          16, 0, 0);
      const u16* gb = Bt + (size_t)(bcol + row) * Kz + kt + off;
      __builtin_amdgcn_global_load_lds(
          (const __attribute__((address_space(1))) void*)gb,
          (__attribute__((address_space(3))) void*)&Bs[(wid * 2 + c) * 512],
          16, 0, 0);
    }
    __syncthreads();

    s16x8 af[4], bfr[4];
#pragma unroll
    for (int i = 0; i < 4; ++i) {
      af[i]  = *reinterpret_cast<const s16x8*>(&As[(wr * 64 + i * 16 + lq) * BKs + g * 8]);
      bfr[i] = *reinterpret_cast<const s16x8*>(&Bs[(wc * 64 + i * 16 + lq) * BKs + g * 8]);
    }
#pragma unroll
    for (int mi = 0; mi < 4; ++mi)
#pragma unroll
      for (int ni = 0; ni < 4; ++ni)
        acc[mi][ni] = __builtin_amdgcn_mfma_f32_16x16x32_bf16(af[mi], bfr[ni], acc[mi][ni], 0, 0, 0);
    __syncthreads();
  }

#pragma unroll
  for (int ni = 0; ni < 4; ++ni) {
    int gcol = bcol + wc * 64 + ni * 16 + lq;
    int h = gcol / 192;
    int rem = gcol - h * 192;
    int tt = rem >> 6;
    int dh = rem & 63;
    float bv = bias[gcol];
    u16* dst = (tt == 0) ? Qo : (tt == 1) ? Ko : Vt;
    float scale = (tt == 0) ? QSCALE : 1.0f;
    bool isv = (tt == 2);
#pragma unroll
    for (int mi = 0; mi < 4; ++mi) {
#pragma unroll
      for (int r = 0; r < 4; ++r) {
        int grow = brow + wr * 64 + mi * 16 + g * 4 + r;
        int bb = grow >> 11;
        int ss = grow & 2047;
        float v = (acc[mi][ni][r] + bv) * scale;
        size_t off = isv ? ((((size_t)bb * Hz + h) * DHz + dh) * Sz + ss)
                         : ((((size_t)bb * Hz + h) * Sz + ss) * DHz + dh);
        dst[off] = f2b(v);
      }
    }
  }
}

// ---------------- causal flash attention ----------------
// grid (8,64) XCD-swizzled (per-XCD bh-chunk of 8 -> KV/XCD L2-resident;
// verified FETCH 143->29MB). Merged dual-q loop (tiles qp and 15-qp).
// NEW: KV super-tile = 128 keys as two 64-key halves staged per ONE barrier
// (4 DMA/thread/super-tile) -> barrier count halved. attn_tile unchanged.
__device__ __forceinline__ void attn_tile(
    const char* KsC, const char* VsC, int kv0, int q0w, int qrow,
    int g, int lq, int p, int cb, int sEven, int sOdd,
    const s16x8& qf0, const s16x8& qf1,
    f32x4 (&o)[4], float& m1, float& l1) {
  if (kv0 > q0w + 15) return;   // wave-uniform

  // ---- swapped QK^T: z[f][r] = S[q=lq][key=kv0+f*16+g*4+r] ----
  f32x4 z[4];
#pragma unroll
  for (int f = 0; f < 4; ++f) {
    int row = f * 16 + lq;
    s16x8 kb0 = *reinterpret_cast<const s16x8*>(KsC + row * 128 + ((g ^ (row & 7)) << 4));
    s16x8 kb1 = *reinterpret_cast<const s16x8*>(KsC + row * 128 + (((g + 4) ^ (row & 7)) << 4));
    f32x4 zz = {0.f, 0.f, 0.f, 0.f};
    zz = __builtin_amdgcn_mfma_f32_16x16x32_bf16(kb0, qf0, zz, 0, 0, 0);
    zz = __builtin_amdgcn_mfma_f32_16x16x32_bf16(kb1, qf1, zz, 0, 0, 0);
    z[f] = zz;
  }

  if (kv0 + 63 > q0w) {  // diagonal tile: causal mask (key > q)
#pragma unroll
    for (int f = 0; f < 4; ++f)
#pragma unroll
      for (int r = 0; r < 4; ++r) {
        int key = kv0 + f * 16 + g * 4 + r;
        if (key > qrow) z[f][r] = -1e30f;
      }
  }

  // ---- row max (max3-friendly chain: fmax(fmax(a,b),c) fuses to v_max3) ----
  float pm;
  pm = fmaxf(fmaxf(z[0][0], z[0][1]), z[0][2]);
  pm = fmaxf(fmaxf(pm, z[0][3]), z[1][0]);
  pm = fmaxf(fmaxf(pm, z[1][1]), z[1][2]);
  pm = fmaxf(fmaxf(pm, z[1][3]), z[2][0]);
  pm = fmaxf(fmaxf(pm, z[2][1]), z[2][2]);
  pm = fmaxf(fmaxf(pm, z[2][3]), z[3][0]);
  pm = fmaxf(fmaxf(pm, z[3][1]), z[3][2]);
  pm = fmaxf(pm, z[3][3]);
  pm = fmaxf(pm, __shfl_xor(pm, 16));
  pm = fmaxf(pm, __shfl_xor(pm, 32));

  // ---- T13 defer-max ----
  if (!__all(pm <= m1 + 8.0f)) {
    float mn = fmaxf(m1, pm);
    float a = exp2f(m1 - mn);
    m1 = mn;
    l1 *= a;
    float a0 = __shfl(a, 4 * g + 0);
    float a1 = __shfl(a, 4 * g + 1);
    float a2 = __shfl(a, 4 * g + 2);
    float a3 = __shfl(a, 4 * g + 3);
#pragma unroll
    for (int ni = 0; ni < 4; ++ni) {
      o[ni][0] *= a0; o[ni][1] *= a1; o[ni][2] *= a2; o[ni][3] *= a3;
    }
  }

  // ---- p = exp2(z - m), sum, pack ----
  float s = 0.f;
  unsigned w[4][2];
#pragma unroll
  for (int f = 0; f < 4; ++f) {
    float p0 = exp2f(z[f][0] - m1);
    float p1 = exp2f(z[f][1] - m1);
    float p2 = exp2f(z[f][2] - m1);
    float p3 = exp2f(z[f][3] - m1);
    s += (p0 + p1) + (p2 + p3);
    w[f][0] = cvt_pk_bf16(p0, p1);
    w[f][1] = cvt_pk_bf16(p2, p3);
  }
  s += __shfl_xor(s, 16);
  s += __shfl_xor(s, 32);
  l1 += s;

  // ---- redistribute P into PV A-fragments: 8 paired shfls ----
  int e0 = __shfl((int)(p ? w[1][0] : w[0][0]), sEven);
  int o0 = __shfl((int)(p ? w[0][0] : w[1][0]), sOdd);
  int e1 = __shfl((int)(p ? w[1][1] : w[0][1]), sEven);
  int o1 = __shfl((int)(p ? w[0][1] : w[1][1]), sOdd);
  int e2 = __shfl((int)(p ? w[3][0] : w[2][0]), sEven);
  int o2 = __shfl((int)(p ? w[2][0] : w[3][0]), sOdd);
  int e3 = __shfl((int)(p ? w[3][1] : w[2][1]), sEven);
  int o3 = __shfl((int)(p ? w[2][1] : w[3][1]), sOdd);
  union { int i[4]; s16x8 v; } A0, A1;
  A0.i[0] = cb ? o0 : e0;
  A0.i[2] = cb ? e0 : o0;
  A0.i[1] = cb ? o1 : e1;
  A0.i[3] = cb ? e1 : o1;
  A1.i[0] = cb ? o2 : e2;
  A1.i[2] = cb ? e2 : o2;
  A1.i[1] = cb ? o3 : e3;
  A1.i[3] = cb ? e3 : o3;

  // ---- PV ----
#pragma unroll
  for (int ni = 0; ni < 4; ++ni) {
    int row = ni * 16 + lq;
    s16x8 vb0 = *reinterpret_cast<const s16x8*>(VsC + row * 128 + ((g ^ (row & 7)) << 4));
    s16x8 vb1 = *reinterpret_cast<const s16x8*>(VsC + row * 128 + (((g + 4) ^ (row & 7)) << 4));
    o[ni] = __builtin_amdgcn_mfma_f32_16x16x32_bf16(A0.v, vb0, o[ni], 0, 0, 0);
    o[ni] = __builtin_amdgcn_mfma_f32_16x16x32_bf16(A1.v, vb1, o[ni], 0, 0, 0);
  }
}

__global__ __launch_bounds__(512, 4) void attn_kernel(
    const u16* __restrict__ Qg, const u16* __restrict__ Kg,
    const u16* __restrict__ Vtg, float* __restrict__ out) {
  __shared__ alignas(16) u16 Ks[2][2][64 * 64];   // [dbuf][half], swizzled K
  __shared__ alignas(16) u16 Vs[2][2][64 * 64];   // [dbuf][half], swizzled V^T

  const int tid = threadIdx.x;
  const int wid = tid >> 6, lane = tid & 63;
  const int g = lane >> 4, lq = lane & 15;

  // XCD-aware swizzle (bijective: 512 % 8 == 0): per-XCD bh-chunk of 8
  const int id = blockIdx.x + 8 * blockIdx.y;
  const int xc = id & 7, rr = id >> 3;
  const int bh = xc * 8 + (rr & 7);
  const int qp = rr >> 3;                         // 0..7

  const size_t base = (size_t)bh * Sz * DHz;
  const int b = bh >> 4, h = bh & 15;

  const int krow = tid >> 3;                      // tile row (key or dh)
  const int sswz = ((tid & 7) ^ (krow & 7)) * 8;  // pre-swizzled source offset

  // P-redistribution geometry (round-5-verified)
  const int p = g & 1;
  const int cb = g >> 1;
  const int sA = 32 * (g & 1) + lq;
  const int sB = sA + 16;
  const int sEven = cb ? sB : sA;
  const int sOdd  = cb ? sA : sB;

  const int qtA = qp, qtB = 15 - qp;
  const int q0wA = qtA * 128 + wid * 16;
  const int q0wB = qtB * 128 + wid * 16;
  const int qrowA = q0wA + lq, qrowB = q0wB + lq;
  const int nT = qtB + 1;                         // 128-key super-tiles

  s16x8 qfA0 = *reinterpret_cast<const s16x8*>(Qg + base + (size_t)qrowA * DHz + g * 8);
  s16x8 qfA1 = *reinterpret_cast<const s16x8*>(Qg + base + (size_t)qrowA * DHz + g * 8 + 32);
  s16x8 qfB0 = *reinterpret_cast<const s16x8*>(Qg + base + (size_t)qrowB * DHz + g * 8);
  s16x8 qfB1 = *reinterpret_cast<const s16x8*>(Qg + base + (size_t)qrowB * DHz + g * 8 + 32);

  f32x4 oA[4] = {}, oB[4] = {};
  float mA = -1e30f, lA = 0.f, mB = -1e30f, lB = 0.f;

#define STAGE_T(bufb, TT) do {                                                  \
    const u16* gk0 = Kg + base + (size_t)((TT) * 128 + krow) * DHz + sswz;      \
    __builtin_amdgcn_global_load_lds(                                           \
        (const __attribute__((address_space(1))) void*)gk0,                     \
        (__attribute__((address_space(3))) void*)&Ks[bufb][0][wid * 512], 16, 0, 0); \
    const u16* gk1 = Kg + base + (size_t)((TT) * 128 + 64 + krow) * DHz + sswz; \
    __builtin_amdgcn_global_load_lds(                                           \
        (const __attribute__((address_space(1))) void*)gk1,                     \
        (__attribute__((address_space(3))) void*)&Ks[bufb][1][wid * 512], 16, 0, 0); \
    const u16* gv0 = Vtg + base + (size_t)krow * Sz + (TT) * 128 + sswz;        \
    __builtin_amdgcn_global_load_lds(                                           \
        (const __attribute__((address_space(1))) void*)gv0,                     \
        (__attribute__((address_space(3))) void*)&Vs[bufb][0][wid * 512], 16, 0, 0); \
    const u16* gv1 = Vtg + base + (size_t)krow * Sz + (TT) * 128 + 64 + sswz;   \
    __builtin_amdgcn_global_load_lds(                                           \
        (const __attribute__((address_space(1))) void*)gv1,                     \
        (__attribute__((address_space(3))) void*)&Vs[bufb][1][wid * 512], 16, 0, 0); \
  } while (0)

  // ---- prologue: stage super-tile 0 into dbuf 0 ----
  STAGE_T(0, 0);
  __syncthreads();

  int cur = 0;
  for (int T = 0; T < nT; ++T) {
    if (T + 1 < nT) STAGE_T(cur ^ 1, T + 1);

#pragma unroll
    for (int hh = 0; hh < 2; ++hh) {
      const char* KsC = (const char*)Ks[cur][hh];
      const char* VsC = (const char*)Vs[cur][hh];
      const int kv0 = T * 128 + hh * 64;
      attn_tile(KsC, VsC, kv0, q0wB, qrowB, g, lq, p, cb, sEven, sOdd,
                qfB0, qfB1, oB, mB, lB);
      attn_tile(KsC, VsC, kv0, q0wA, qrowA, g, lq, p, cb, sEven, sOdd,
                qfA0, qfA1, oA, mA, lA);
    }

    __syncthreads();
    cur ^= 1;
  }

  // ---- write out [B][S][H][DH] f32 for both q-tiles ----
#pragma unroll
  for (int half = 0; half < 2; ++half) {
    const int q0w = half ? q0wB : q0wA;
    f32x4* o = half ? oB : oA;
    float l1 = half ? lB : lA;
    float lr0 = __shfl(l1, 4 * g + 0);
    float lr1 = __shfl(l1, 4 * g + 1);
    float lr2 = __shfl(l1, 4 * g + 2);
    float lr3 = __shfl(l1, 4 * g + 3);
    float inv[4] = {1.0f / lr0, 1.0f / lr1, 1.0f / lr2, 1.0f / lr3};
#pragma unroll
    for (int r = 0; r < 4; ++r) {
      int s = q0w + g * 4 + r;
      float* op = out + (((size_t)b * Sz + s) * Hz + h) * DHz;
#pragma unroll
      for (int ni = 0; ni < 4; ++ni)
        op[ni * 16 + lq] = o[ni][r] * inv[r];
    }
  }
}

extern "C" void kernel_launch(void* const* d_in, const int* in_sizes, int n_in,
                              void* d_out, int out_size, void* d_ws, size_t ws_size,
                              hipStream_t stream) {
  const float* x    = (const float*)d_in[0];
  const float* W    = (const float*)d_in[1];
  const float* bias = (const float*)d_in[2];
  float* out = (float*)d_out;

  char* ws = (char*)d_ws;
  u16* xb = (u16*)(ws);                      // 16 MB
  u16* wt = (u16*)(ws + 16777216);           // 6 MB
  u16* Qb = (u16*)(ws + 23068672);           // 16 MB
  u16* Kb = (u16*)(ws + 39845888);           // 16 MB
  u16* Vtb = (u16*)(ws + 56623104);          // 16 MB  (transposed: [b][h][dh][s])

  prep<<<8192 + 3072, 256, 0, stream>>>(x, xb, W, wt);
  qkv_gemm<<<dim3(Mz / BM, N3z / BN), 256, 0, stream>>>(xb, wt, bias, Qb, Kb, Vtb);
  attn_kernel<<<dim3(8, Bz * Hz), 512, 0, stream>>>(Qb, Kb, Vtb, out);
}